// Round 7
// baseline (1766.733 us; speedup 1.0000x reference)
//
#include <hip/hip_runtime.h>

typedef unsigned int u32;
typedef float f32x2 __attribute__((ext_vector_type(2)));
typedef float f32x4 __attribute__((ext_vector_type(4)));

#define N_NODE_ 500
#define N_POD_  20000
#define N_SVC_  2000
#define N_TOT_  22500
#define T_ 16
#define F_ 64
#define H_ 128
#define O_ 64

// ---------------- static device scratch (no d_ws use) ----------------
// float region
#define OF_OUTD_SC  0
#define OF_IND_SC   2000
#define OF_OUTD_IN  4000
#define OF_IND_IN   24000
#define OF_OUTD_NI  24500
#define OF_IND_NI   25000
#define OF_OUTD_II  45000
#define OF_IND_II   65000
#define OF_OUTD_SI  85000
#define OF_IND_SI   87000
#define OF_OUTD_IS  107000
#define OF_IND_IS   127000
#define OF_DEG_END  129000
// LSTM weights, gate-interleaved transposed layout:
//   W[k][j][q] at offset k*256 + j*4 + q, value = W_orig[q*64 + j][k]
// OF_W0: [192][256]  (k<128: Wih0, k>=128: Whh0)
// OF_W1: [128][256]  (k<64:  Wih1, k>=64:  Whh1)
#define OF_W0       129024
#define OF_W1       (129024 + 49152)
#define G_F_SIZE    (129024 + 81920)
// int region (cnt doubles as fill cursor after re-zero)
#define OI_CNT_IN 0
#define OI_CNT_NI 500
#define OI_CNT_II 20500
#define OI_CNT_SI 40500
#define OI_CNT_SC 60500
#define OI_CNT_IS 62500
#define OI_CNT_END 64500
#define OI_OFF_IN 64500
#define OI_OFF_NI 65001
#define OI_OFF_II 85002
#define OI_OFF_SI 105003
#define OI_OFF_SC 125004
#define OI_OFF_IS 127005
#define OI_CSR_IN 129006
#define OI_CSR_NI 149006
#define OI_CSR_II 169006
#define OI_CSR_SI 269006
#define OI_CSR_SC 289006
#define OI_CSR_IS 305006
#define G_I_SIZE  325006

__device__ __align__(16) float g_f[G_F_SIZE];
__device__ int g_i[G_I_SIZE];

__device__ __forceinline__ float sigf(float x) { return 1.0f / (1.0f + __expf(-x)); }

// fast tanh via v_exp: tanh(x) = sign(x) * (1 - 2/(exp(2|x|)+1)); exact at 0, ±1 at inf
__device__ __forceinline__ float tanhf_fast(float x) {
  float ax = fabsf(x);
  float e = __expf(2.0f * ax);
  float t = 1.0f - 2.0f / (e + 1.0f);
  return copysignf(t, x);
}

// ---- packed fp32 FMA (VOP3P): 2 fp32 FMAs / instruction ----
// Operands are ext_vector_type(2) floats -> guaranteed VGPR-pair class for "v".
// pk_lo: a.lo += x.lo*w.lo ; a.hi += x.lo*w.hi   (broadcast x.lo into both halves)
__device__ __forceinline__ void pk_lo(f32x2& a, f32x2 x, f32x2 w) {
  asm("v_pk_fma_f32 %0, %1, %2, %0 op_sel:[0,0,0] op_sel_hi:[0,1,1]"
      : "+v"(a) : "v"(x), "v"(w));
}
// pk_hi: a.lo += x.hi*w.lo ; a.hi += x.hi*w.hi   (broadcast x.hi into both halves)
__device__ __forceinline__ void pk_hi(f32x2& a, f32x2 x, f32x2 w) {
  asm("v_pk_fma_f32 %0, %1, %2, %0 op_sel:[1,0,0] op_sel_hi:[1,1,1]"
      : "+v"(a) : "v"(x), "v"(w));
}

// ---------- zero the accumulated scratch regions (every launch) ----------
__global__ void zero_k() {
  int i = blockIdx.x * 256 + threadIdx.x;
  if (i < OF_DEG_END + 24) g_f[i] = 0.0f;
  if (i < OI_CNT_END) g_i[i] = 0;
}

// ---------- per-relation metadata (passed by value) ----------
struct Rels {
  const int* src[6];
  const int* dst[6];
  int n[6];
  int o_outd[6];
  int o_ind[6];
  int o_cnt[6];
  int o_off[6];
  int o_csr[6];
};

// all 6 relations in one 2D launch: y = relation
__global__ void deg_all_k(Rels R) {
  int rel = blockIdx.y;
  int e = blockIdx.x * 256 + threadIdx.x;
  if (e < R.n[rel]) {
    atomicAdd(&g_f[R.o_outd[rel] + R.src[rel][e]], 1.0f);
    atomicAdd(&g_f[R.o_ind[rel] + R.dst[rel][e]], 1.0f);
    atomicAdd(&g_i[R.o_cnt[rel] + R.dst[rel][e]], 1);
  }
}

__global__ void fill_all_k(Rels R) {
  int rel = blockIdx.y;
  int e = blockIdx.x * 256 + threadIdx.x;
  if (e < R.n[rel]) {
    int d = R.dst[rel][e];
    int p = atomicAdd(&g_i[R.o_cnt[rel] + d], 1);
    g_i[R.o_csr[rel] + g_i[R.o_off[rel] + d] + p] = R.src[rel][e];
  }
}

// rsqrt of all degrees + all 4 LSTM weight transposes, one launch
__device__ __forceinline__ void tw_one(const float* __restrict__ in, int o_out, int K, int idx) {
  int r = idx / K, k = idx - r * K;
  int q = r >> 6, j = r & 63;
  g_f[o_out + k * 256 + (j << 2) + q] = in[idx];
}

#define PREP2_TOT (OF_DEG_END + 32768 + 16384 + 16384 + 16384)
__global__ void prep2_k(const float* __restrict__ Wih0, const float* __restrict__ Whh0,
                        const float* __restrict__ Wih1, const float* __restrict__ Whh1) {
  int i = blockIdx.x * 256 + threadIdx.x;
  if (i < OF_DEG_END) { g_f[i] = rsqrtf(fmaxf(g_f[i], 1.0f)); return; }
  int j = i - OF_DEG_END;
  if (j < 32768) { tw_one(Wih0, OF_W0, 128, j); return; }
  j -= 32768;
  if (j < 16384) { tw_one(Whh0, OF_W0 + 32768, 64, j); return; }
  j -= 16384;
  if (j < 16384) { tw_one(Wih1, OF_W1, 64, j); return; }
  j -= 16384;
  if (j < 16384) { tw_one(Whh1, OF_W1 + 16384, 64, j); return; }
}

// ---------- 6 single-block exclusive scans (also re-zeroes cnt for fill) ----------
__global__ void exscan6_k() {
  const int cnto[6] = {OI_CNT_IN, OI_CNT_NI, OI_CNT_II, OI_CNT_SI, OI_CNT_SC, OI_CNT_IS};
  const int offo[6] = {OI_OFF_IN, OI_OFF_NI, OI_OFF_II, OI_OFF_SI, OI_OFF_SC, OI_OFF_IS};
  const int ns[6] = {500, 20000, 20000, 20000, 2000, 2000};
  int rel = blockIdx.x;
  int* cnt = g_i + cnto[rel];
  int* off = g_i + offo[rel];
  int n = ns[rel];
  __shared__ int base_s[257];
  __shared__ int part[256];
  int tid = threadIdx.x;
  int chunk = (n + 255) >> 8;
  int lo = tid * chunk;
  int hi = lo + chunk; if (hi > n) hi = n;
  int s = 0;
  for (int i = lo; i < hi; ++i) s += cnt[i];
  part[tid] = s;
  __syncthreads();
  if (tid == 0) {
    int run = 0;
    for (int j = 0; j < 256; ++j) { base_s[j] = run; run += part[j]; }
    base_s[256] = run;
  }
  __syncthreads();
  int run = base_s[tid];
  for (int i = lo; i < hi; ++i) { off[i] = run; run += cnt[i]; cnt[i] = 0; }
  if (tid == 0) off[n] = base_s[256];
}

// ---------- fused gather + GEMM per dst node ----------
// block = one dst node; 256 threads; out[t][h] = relu(scale*(sum_rel m_rel*rsqrt(ind)*W_rel + b_rel))
template <int NREL>
__global__ __launch_bounds__(256) void gconv_gather_k(
    const float* __restrict__ x0, const float* __restrict__ x1, const float* __restrict__ x2,
    int off0, int off1, int off2, int csr0, int csr1, int csr2,
    int od0, int od1, int od2, int id0, int id1, int id2,
    const float* __restrict__ W0, const float* __restrict__ W1, const float* __restrict__ W2,
    const float* __restrict__ b0, const float* __restrict__ b1, const float* __restrict__ b2,
    float scale, float* __restrict__ outp) {
  const float* xs_[3] = {x0, x1, x2};
  const int offs[3] = {off0, off1, off2};
  const int csrs[3] = {csr0, csr1, csr2};
  const int ods[3] = {od0, od1, od2};
  const int ids[3] = {id0, id1, id2};
  const float* Ws[3] = {W0, W1, W2};
  const float* bs[3] = {b0, b1, b2};

  int node = blockIdx.x;
  int tid = threadIdx.x;
  int c = tid & 127;
  int rg = tid >> 7;  // 0/1 -> t rows [0,8) / [8,16)
  __shared__ float msh[T_][F_];  // flat index = t*64+f

  float bb = 0.0f;
#pragma unroll
  for (int rel = 0; rel < NREL; ++rel) bb += bs[rel][c];
  float acc[8];
#pragma unroll
  for (int i = 0; i < 8; ++i) acc[i] = bb;

#pragma unroll
  for (int rel = 0; rel < NREL; ++rel) {
    int e0 = g_i[offs[rel] + node], e1 = g_i[offs[rel] + node + 1];
    const int* csr = g_i + csrs[rel];
    const float* od = g_f + ods[rel];
    const float* xr = xs_[rel];
    // thread owns 4 contiguous elements of the 1024-float [T,F] row
    float a0 = 0.0f, a1 = 0.0f, a2 = 0.0f, a3 = 0.0f;
    for (int e = e0; e < e1; ++e) {
      int s = csr[e];
      float rs = od[s];
      float4 v = ((const float4*)(xr + (size_t)s * 1024))[tid];
      a0 += v.x * rs;
      a1 += v.y * rs;
      a2 += v.z * rs;
      a3 += v.w * rs;
    }
    __syncthreads();  // previous rel's GEMM reads done
    float* mf = &msh[0][0];
    mf[tid * 4 + 0] = a0;
    mf[tid * 4 + 1] = a1;
    mf[tid * 4 + 2] = a2;
    mf[tid * 4 + 3] = a3;
    __syncthreads();
    float rind = g_f[ids[rel] + node];
    const float* W = Ws[rel];
#pragma unroll 4
    for (int f = 0; f < F_; ++f) {
      float w = W[f * H_ + c] * rind;
#pragma unroll
      for (int i = 0; i < 8; ++i) acc[i] += msh[rg * 8 + i][f] * w;
    }
  }
  float* o = outp + (size_t)node * (T_ * H_);
#pragma unroll
  for (int i = 0; i < 8; ++i) {
    float v = acc[i] * scale;
    o[(rg * 8 + i) * H_ + c] = fmaxf(v, 0.0f);
  }
}

// ---------- 2-layer LSTM: LDS-broadcast + packed fp32 FMA ----------
// Round-3 verified geometry: 512 blocks x 4 waves, RW=11 rows/wave
// (22528 rows, 2 blocks/CU, 2 waves/SIMD). Round-4 lesson: more waves
// scales W L2 traffic and regresses. Round-5 lesson: staging W through
// LDS overloads the DS pipe + barrier-serializes; W streams from L2
// directly (VMEM pipe). This round: halve FMA issue slots with
// v_pk_fma_f32 (2 fp32 FMAs/instr, x broadcast via op_sel) - acc pairs
// (i,f) and (g,o) match the gate-interleaved W layout's adjacent float2s.
// Same summation order as round 3 -> identical numerics.
#define RW 11

__device__ __forceinline__ void gemv_pk(f32x2 accA[RW], f32x2 accB[RW], const float* xrow0,
                                        const f32x4* __restrict__ Wb, int nk4, int l) {
#pragma unroll 2
  for (int k4 = 0; k4 < nk4; ++k4) {
    // 4 consecutive k rows; each row: f32x4 per lane = (wi,wf | wg,wo)
    const f32x4* wp = Wb + (k4 << 8) + l;
    f32x4 w0 = wp[0], w1 = wp[64], w2 = wp[128], w3 = wp[192];
    f32x2 w0A = __builtin_shufflevector(w0, w0, 0, 1), w0B = __builtin_shufflevector(w0, w0, 2, 3);
    f32x2 w1A = __builtin_shufflevector(w1, w1, 0, 1), w1B = __builtin_shufflevector(w1, w1, 2, 3);
    f32x2 w2A = __builtin_shufflevector(w2, w2, 0, 1), w2B = __builtin_shufflevector(w2, w2, 2, 3);
    f32x2 w3A = __builtin_shufflevector(w3, w3, 0, 1), w3B = __builtin_shufflevector(w3, w3, 2, 3);
#pragma unroll
    for (int r = 0; r < RW; ++r) {
      f32x4 xv = *(const f32x4*)(xrow0 + r * 256 + k4 * 4);  // uniform ds_read_b128
      f32x2 xp0 = __builtin_shufflevector(xv, xv, 0, 1);
      f32x2 xp1 = __builtin_shufflevector(xv, xv, 2, 3);
      pk_lo(accA[r], xp0, w0A); pk_lo(accB[r], xp0, w0B);
      pk_hi(accA[r], xp0, w1A); pk_hi(accB[r], xp0, w1B);
      pk_lo(accA[r], xp1, w2A); pk_lo(accB[r], xp1, w2B);
      pk_hi(accA[r], xp1, w3A); pk_hi(accB[r], xp1, w3B);
    }
  }
}

__global__ __launch_bounds__(256, 2) void lstm_pk_k(
    const float* __restrict__ feat,  // [N_TOT,16,128] fp32 (post-relu)
    const float* __restrict__ bih0, const float* __restrict__ bhh0,
    const float* __restrict__ bih1, const float* __restrict__ bhh1,
    float* __restrict__ out2) {
  const f32x4* W0v = (const f32x4*)(g_f + OF_W0);  // [192][64] f32x4
  const f32x4* W1v = (const f32x4*)(g_f + OF_W1);  // [128][64] f32x4
  __shared__ __align__(16) float xh[4][RW][256];   // 45056 B
  int tid = threadIdx.x;
  int l = tid & 63;
  int wid = tid >> 6;
  int row0 = (blockIdx.x * 4 + wid) * RW;
  float* xw = &xh[wid][0][0];

  // gate pairs: A = (i,f), B = (g,o); col q*64+l
  f32x2 bbA0 = {bih0[l] + bhh0[l], bih0[64 + l] + bhh0[64 + l]};
  f32x2 bbB0 = {bih0[128 + l] + bhh0[128 + l], bih0[192 + l] + bhh0[192 + l]};
  f32x2 bbA1 = {bih1[l] + bhh1[l], bih1[64 + l] + bhh1[64 + l]};
  f32x2 bbB1 = {bih1[128 + l] + bhh1[128 + l], bih1[192 + l] + bhh1[192 + l]};

  const float* xb[RW];
  bool vld[RW];
#pragma unroll
  for (int r = 0; r < RW; ++r) {
    int row = row0 + r;
    vld[r] = row < N_TOT_;
    xb[r] = feat + (size_t)(vld[r] ? row : 0) * (T_ * H_);
  }

  float c0[RW] = {}, c1[RW] = {};
  // zero h0/h1 regions (wave-private, no barrier needed)
#pragma unroll
  for (int r = 0; r < RW; ++r) {
    xw[r * 256 + 128 + l] = 0.0f;
    xw[r * 256 + 192 + l] = 0.0f;
  }

  // preload x for t=0
  float xn0[RW], xn1[RW];
#pragma unroll
  for (int r = 0; r < RW; ++r) {
    xn0[r] = xb[r][l];
    xn1[r] = xb[r][64 + l];
  }

  for (int t = 0; t < T_; ++t) {
    // stage x_t from prefetch regs into the wave's LDS slice
#pragma unroll
    for (int r = 0; r < RW; ++r) {
      xw[r * 256 + l] = xn0[r];
      xw[r * 256 + 64 + l] = xn1[r];
    }
    // prefetch x_{t+1}: latency hides under both gemvs (t=15 re-reads t=0)
    int tn = (t + 1) & 15;
#pragma unroll
    for (int r = 0; r < RW; ++r) {
      xn0[r] = xb[r][tn * H_ + l];
      xn1[r] = xb[r][tn * H_ + 64 + l];
    }

    f32x2 accA[RW], accB[RW];
#pragma unroll
    for (int r = 0; r < RW; ++r) { accA[r] = bbA0; accB[r] = bbB0; }

    // layer 0: [x_t | h0_prev] @ [Wih0 | Whh0], K=192 contiguous in LDS
    gemv_pk(accA, accB, xw, W0v, 48, l);

#pragma unroll
    for (int r = 0; r < RW; ++r) {
      float iv = sigf(accA[r][0]);
      float fv = sigf(accA[r][1]);
      float gv = tanhf_fast(accB[r][0]);
      float ov = sigf(accB[r][1]);
      float cc = fv * c0[r] + iv * gv;
      c0[r] = cc;
      xw[r * 256 + 128 + l] = ov * tanhf_fast(cc);  // h0_new -> LDS
    }

#pragma unroll
    for (int r = 0; r < RW; ++r) { accA[r] = bbA1; accB[r] = bbB1; }

    // layer 1: [h0_new | h1_prev] @ [Wih1 | Whh1], K=128 contiguous in LDS
    gemv_pk(accA, accB, xw + 128, W1v, 32, l);

#pragma unroll
    for (int r = 0; r < RW; ++r) {
      float iv = sigf(accA[r][0]);
      float fv = sigf(accA[r][1]);
      float gv = tanhf_fast(accB[r][0]);
      float ov = sigf(accB[r][1]);
      float cc = fv * c1[r] + iv * gv;
      c1[r] = cc;
      float hh = ov * tanhf_fast(cc);
      xw[r * 256 + 192 + l] = hh;  // h1_new -> LDS
      if (vld[r]) out2[((size_t)(row0 + r) * T_ + t) * O_ + l] = fmaxf(hh, 0.0f);
    }
  }
}

extern "C" void kernel_launch(void* const* d_in, const int* in_sizes, int n_in,
                              void* d_out, int out_size, void* d_ws, size_t ws_size,
                              hipStream_t stream) {
  (void)in_sizes; (void)n_in; (void)out_size; (void)d_ws; (void)ws_size;
  const float* x_node = (const float*)d_in[0];
  const float* x_pod  = (const float*)d_in[1];
  const float* x_svc  = (const float*)d_in[2];
  const int* sc_src = (const int*)d_in[3];
  const int* sc_dst = (const int*)d_in[4];
  const int* in_src = (const int*)d_in[5];
  const int* in_dst = (const int*)d_in[6];
  const int* ni_src = (const int*)d_in[7];
  const int* ni_dst = (const int*)d_in[8];
  const int* ii_src = (const int*)d_in[9];
  const int* ii_dst = (const int*)d_in[10];
  const int* si_src = (const int*)d_in[11];
  const int* si_dst = (const int*)d_in[12];
  const int* is_src = (const int*)d_in[13];
  const int* is_dst = (const int*)d_in[14];
  const float* W_sc = (const float*)d_in[15]; const float* b_sc = (const float*)d_in[16];
  const float* W_in = (const float*)d_in[17]; const float* b_in = (const float*)d_in[18];
  const float* W_ni = (const float*)d_in[19]; const float* b_ni = (const float*)d_in[20];
  const float* W_ii = (const float*)d_in[21]; const float* b_ii = (const float*)d_in[22];
  const float* W_si = (const float*)d_in[23]; const float* b_si = (const float*)d_in[24];
  const float* W_is = (const float*)d_in[25]; const float* b_is = (const float*)d_in[26];
  const float* Wih0 = (const float*)d_in[27]; const float* Whh0 = (const float*)d_in[28];
  const float* bih0 = (const float*)d_in[29]; const float* bhh0 = (const float*)d_in[30];
  const float* Wih1 = (const float*)d_in[31]; const float* Whh1 = (const float*)d_in[32];
  const float* bih1 = (const float*)d_in[33]; const float* bhh1 = (const float*)d_in[34];

  float* out_feat = (float*)d_out;
  float* out_h = out_feat + (size_t)N_TOT_ * T_ * H_;  // +46,080,000

  Rels R;
  R.src[0] = in_src; R.dst[0] = in_dst; R.n[0] = 20000;
  R.o_outd[0] = OF_OUTD_IN; R.o_ind[0] = OF_IND_IN; R.o_cnt[0] = OI_CNT_IN;
  R.o_off[0] = OI_OFF_IN; R.o_csr[0] = OI_CSR_IN;
  R.src[1] = ni_src; R.dst[1] = ni_dst; R.n[1] = 20000;
  R.o_outd[1] = OF_OUTD_NI; R.o_ind[1] = OF_IND_NI; R.o_cnt[1] = OI_CNT_NI;
  R.o_off[1] = OI_OFF_NI; R.o_csr[1] = OI_CSR_NI;
  R.src[2] = ii_src; R.dst[2] = ii_dst; R.n[2] = 100000;
  R.o_outd[2] = OF_OUTD_II; R.o_ind[2] = OF_IND_II; R.o_cnt[2] = OI_CNT_II;
  R.o_off[2] = OI_OFF_II; R.o_csr[2] = OI_CSR_II;
  R.src[3] = si_src; R.dst[3] = si_dst; R.n[3] = 20000;
  R.o_outd[3] = OF_OUTD_SI; R.o_ind[3] = OF_IND_SI; R.o_cnt[3] = OI_CNT_SI;
  R.o_off[3] = OI_OFF_SI; R.o_csr[3] = OI_CSR_SI;
  R.src[4] = sc_src; R.dst[4] = sc_dst; R.n[4] = 16000;
  R.o_outd[4] = OF_OUTD_SC; R.o_ind[4] = OF_IND_SC; R.o_cnt[4] = OI_CNT_SC;
  R.o_off[4] = OI_OFF_SC; R.o_csr[4] = OI_CSR_SC;
  R.src[5] = is_src; R.dst[5] = is_dst; R.n[5] = 20000;
  R.o_outd[5] = OF_OUTD_IS; R.o_ind[5] = OF_IND_IS; R.o_cnt[5] = OI_CNT_IS;
  R.o_off[5] = OI_OFF_IS; R.o_csr[5] = OI_CSR_IS;

  // zero accumulated scratch
  zero_k<<<(OF_DEG_END + 24 + 255) / 256, 256, 0, stream>>>();

  // degrees + counts, all relations (2D grid; small rels exit early)
  deg_all_k<<<dim3((100000 + 255) / 256, 6), 256, 0, stream>>>(R);

  // rsqrt degrees + all 4 LSTM weight transposes
  prep2_k<<<(PREP2_TOT + 255) / 256, 256, 0, stream>>>(Wih0, Whh0, Wih1, Whh1);

  // CSR build (exscan also re-zeroes cnt for use as fill cursor)
  exscan6_k<<<6, 256, 0, stream>>>();
  fill_all_k<<<dim3((100000 + 255) / 256, 6), 256, 0, stream>>>(R);

  // fused gather + GEMM per dst type
  gconv_gather_k<1><<<N_NODE_, 256, 0, stream>>>(
      x_pod, nullptr, nullptr, OI_OFF_IN, 0, 0, OI_CSR_IN, 0, 0,
      OF_OUTD_IN, 0, 0, OF_IND_IN, 0, 0,
      W_in, nullptr, nullptr, b_in, nullptr, nullptr, 1.0f, out_feat);
  gconv_gather_k<3><<<N_POD_, 256, 0, stream>>>(
      x_node, x_pod, x_svc, OI_OFF_NI, OI_OFF_II, OI_OFF_SI, OI_CSR_NI, OI_CSR_II, OI_CSR_SI,
      OF_OUTD_NI, OF_OUTD_II, OF_OUTD_SI, OF_IND_NI, OF_IND_II, OF_IND_SI,
      W_ni, W_ii, W_si, b_ni, b_ii, b_si, 1.0f / 3.0f,
      out_feat + (size_t)N_NODE_ * (T_ * H_));
  gconv_gather_k<2><<<N_SVC_, 256, 0, stream>>>(
      x_svc, x_pod, nullptr, OI_OFF_SC, OI_OFF_IS, 0, OI_CSR_SC, OI_CSR_IS, 0,
      OF_OUTD_SC, OF_OUTD_IS, 0, OF_IND_SC, OF_IND_IS, 0,
      W_sc, W_is, nullptr, b_sc, b_is, nullptr, 0.5f,
      out_feat + (size_t)(N_NODE_ + N_POD_) * (T_ * H_));

  // 2-layer LSTM: round-3 structure + v_pk_fma_f32 (2 FMAs/instr)
  lstm_pk_k<<<512, 256, 0, stream>>>(
      out_feat, bih0, bhh0, bih1, bhh1, out_h);
}